// Round 5
// baseline (269.930 us; speedup 1.0000x reference)
//
#include <hip/hip_runtime.h>

#define N_BATCH 256
#define SEQ     2048
#define L       50
#define CORE    58                  // output rows per block
#define HALO    3                   // iteration dependency radius
#define SP      72                  // p row stride in bf16 (144 B, 16B-aligned)
#define SB      72                  // B row stride in bf16
#define ITER    3
#define RSZ     (64 * SP)           // 4608 shorts = 9216 B per LDS region

#define L2E 1.4426950408889634f
#define LN2 0.6931471805599453f

typedef __attribute__((ext_vector_type(8))) short bf16x8;
typedef __attribute__((ext_vector_type(4))) float f32x4;

__device__ __forceinline__ unsigned short f2b(float f) {
    unsigned int u = __builtin_bit_cast(unsigned int, f);
    u += 0x7FFFu + ((u >> 16) & 1u);            // RTNE
    return (unsigned short)(u >> 16);
}

// gfx950 packed f32->bf16 (RTNE)
__device__ __forceinline__ unsigned int cvt_pk_bf16(float lo, float hi) {
    unsigned int r;
    asm("v_cvt_pk_bf16_f32 %0, %1, %2" : "=v"(r) : "v"(lo), "v"(hi));
    return r;
}

template <int CTRL>
__device__ __forceinline__ float dpp_mov_f32(float x) {
    int xi = __builtin_bit_cast(int, x);
    int r  = __builtin_amdgcn_update_dpp(xi, xi, CTRL, 0xF, 0xF, false);
    return __builtin_bit_cast(float, r);
}

// 16-lane (nloc) sum entirely on the VALU:
// quad_perm xor1 (0xB1), xor2 (0x4E), then row_ror:4 (0x124) + row_ror:8 (0x128)
__device__ __forceinline__ float rowsum16(float s) {
    s += dpp_mov_f32<0xB1>(s);
    s += dpp_mov_f32<0x4E>(s);
    s += dpp_mov_f32<0x124>(s);
    s += dpp_mov_f32<0x128>(s);
    return s;
}

__device__ __forceinline__ float fexp2(float x) {
#if __has_builtin(__builtin_amdgcn_exp2f)
    return __builtin_amdgcn_exp2f(x);
#else
    return __expf(x * LN2);
#endif
}

// softmax of one 50-wide row slice (log2e domain) + normalized bf16 pack +
// single conflict-free ds_write_b64. x0..x3 are this lane's 4 elements
// (cols nloc, 16+nloc, 32+nloc, 48+nloc); v3 masks cols >= 50.
__device__ __forceinline__ void softmax_row_write(
    float x0, float x1, float x2, float x3, bool v3, bool valid,
    unsigned short* dst)
{
    float e0 = fexp2(x0);
    float e1 = fexp2(x1);
    float e2 = fexp2(x2);
    float e3 = v3 ? fexp2(x3) : 0.f;
    float s  = rowsum16(e0 + e1 + e2 + e3);
    float inv = valid ? __builtin_amdgcn_rcpf(s) : 0.f;   // 0 -> OOR rows give p=0
    uint2 pk;
    pk.x = cvt_pk_bf16(e0 * inv, e1 * inv);
    pk.y = cvt_pk_bf16(e2 * inv, e3 * inv);
    *(uint2*)dst = pk;
}

// k-dim permutation: k' = (k&15)*4 + (k>>4). Applied to BOTH p writes and
// BL/BR staging -> contraction unchanged (bijection on k), but each lane's 4
// softmax outputs land contiguously -> one ds_write_b64, conflict-free.
#define KPERM(k) ((((k) & 15) << 2) | ((k) >> 4))

// waves_per_eu PINNED (5,5): budget ~96-102 regs for a ~93-reg live set
// (bL 32 + umm 16 + acc 16 + mk 4 + temps). bR now lives in LDS (read per
// iteration) instead of 32 persistent VGPRs -- that is what makes 5 waves/EU
// fit. History: a (4,8) RANGE spilled the B file (round 2, +368 MB scratch
// writes); (4,4)+both-B-in-regs still spilled 1 reg (round 3, +35 MB).
// Tripwire: WRITE_SIZE > ~110 MB means spill -> revert to (4,4)+reg-bR.
__global__ __attribute__((amdgpu_waves_per_eu(5, 5))) __launch_bounds__(256)
void mfvi_kernel(
    const float* __restrict__ unary,
    const float* __restrict__ mask,
    const float* __restrict__ trans,   // [L][L]
    const float* __restrict__ tstart,  // [L]
    const float* __restrict__ tend,    // [L]
    float* __restrict__ out)
{
    // LDS map (shorts): [p0: 0..4608) [p1: 4608..9216) [BR: 9216..13824)
    //  - BL staging is transient in the p0 region (extracted to regs)
    //  - BR is PERSISTENT (read as B-fragments every iteration)
    //  - p double-buffer in p0/p1 -> ONE barrier per iteration
    //  - fp32 out-stage (11600 B) reuses p0+p1 at the end
    __shared__ __attribute__((aligned(16))) unsigned short SH[3 * RSZ]; // 27648 B
    unsigned short* BLs = SH;               // transient: BL[n][k'] = T[k][n]
    unsigned short* BRs = SH + 2 * RSZ;     // persistent: BR[n][k'] = T[n][k]
    float* stage = (float*)SH;

    const int tid   = threadIdx.x;
    const int lane  = tid & 63;
    const int wave  = tid >> 6;
    const int nloc  = lane & 15;
    const int quad  = lane >> 4;
    const int nb    = blockIdx.y;
    const int s0    = blockIdx.x * CORE;
    const int tile0 = s0 - HALO + wave * 16;   // global seq row of this wave's tile row 0

    // ---------- early global loads (in flight across LDS setup) ----------
    float uraw[4][4], mk[4], tev[4];
#pragma unroll
    for (int nt = 0; nt < 4; ++nt) {
        int c = nt * 16 + nloc;
        tev[nt] = (c < L) ? tend[c] : 0.f;
    }
#pragma unroll
    for (int reg = 0; reg < 4; ++reg) {
        int g = tile0 + quad * 4 + reg;
        bool in = (unsigned)g < (unsigned)SEQ;
        mk[reg] = in ? mask[nb * SEQ + g] : 0.f;
#pragma unroll
        for (int nt = 0; nt < 4; ++nt) {
            int c = nt * 16 + nloc;
            bool cv = in && (c < L);
            uraw[nt][reg] = cv ? unary[((size_t)nb * SEQ + g) * L + c] : 0.f;
        }
    }

    // ---------- zero staging regions (BL area + BR; pad rows/cols -> finite 0) ----------
    {
        uint4 z; z.x = 0u; z.y = 0u; z.z = 0u; z.w = 0u;
        uint4* p = (uint4*)SH;
        // region 0: shorts [0, RSZ)  -> uint4 [0, RSZ/8)
        // region 2: shorts [2*RSZ, 3*RSZ) -> uint4 [2*RSZ/8, 3*RSZ/8)
        for (int i = tid; i < (2 * RSZ) / 8; i += 256) {
            int j = (i < RSZ / 8) ? i : i + RSZ / 8;   // skip p1 region
            p[j] = z;
        }
    }
    __syncthreads();

    // ---------- stage T: coalesced read, k-permuted LDS scatter ----------
    for (int i = tid; i < L * L; i += 256) {
        int r = i / L, c = i - r * L;
        unsigned short v = f2b(trans[i]);
        BLs[c * SB + KPERM(r)] = v;
        BRs[r * SB + KPERM(c)] = v;
    }
    __syncthreads();

    // ---------- bL fragments -> registers (32 VGPRs, persistent) ----------
    bf16x8 bL[2][4];
#pragma unroll
    for (int kk = 0; kk < 2; ++kk)
#pragma unroll
        for (int nt = 0; nt < 4; ++nt) {
            int off = (nt * 16 + nloc) * SB + kk * 32 + quad * 8;
            bL[kk][nt] = *(const bf16x8*)&BLs[off];
        }
    __syncthreads();   // BL staging dead; p0 region live from here

    // ---------- umm (log2e domain) + initial q in-place in uraw ----------
    // q' = q*log2e; softmax(q) == 2^q' normalized; final out = q'_final * ln2.
    float umm[4][4];
#pragma unroll
    for (int reg = 0; reg < 4; ++reg) {
        int g = tile0 + quad * 4 + reg;
#pragma unroll
        for (int nt = 0; nt < 4; ++nt) {
            float bnd = tev[nt];
            if (g == 0) {                      // exactly one row in the whole grid
                int c = nt * 16 + nloc;
                bnd = (c < L) ? tstart[c] : 0.f;
            }
            float qv  = uraw[nt][reg] * mk[reg];
            uraw[nt][reg] = qv * L2E;                    // q'_init
            umm[nt][reg]  = (qv + bnd) * (mk[reg] * L2E);
        }
        mk[reg] *= L2E;   // fused scale: softmax input = umm' + mk'*acc
    }

    const int myrow = wave * 16 + quad * 4;
    int slL = wave * 16 + nloc - 1; if (slL < 0)  slL = 0;   // clamped -> don't-care rows
    int slR = wave * 16 + nloc + 1; if (slR > 63) slR = 63;
    const int pw_off  = myrow * SP + 4 * nloc;   // b64 write base (8B-aligned)
    const int paL_off = slL * SP + quad * 8;
    const int paR_off = slR * SP + quad * 8;
    // bR fragment base: per-lane n-row + quad sub-offset; nt/kk via immediates
    const unsigned short* bRbase = BRs + nloc * SB + quad * 8;
    const int grow0 = tile0 + quad * 4;
    const bool v3 = (nloc < 2);                  // col 48+nloc < 50

    // ---------- prologue: softmax#1 from q'_init, write p0 ----------
#pragma unroll
    for (int reg = 0; reg < 4; ++reg) {
        bool valid = (unsigned)(grow0 + reg) < (unsigned)SEQ;
        softmax_row_write(uraw[0][reg], uraw[1][reg], uraw[2][reg], uraw[3][reg],
                          v3, valid, SH + pw_off + reg * SP);
    }
    __syncthreads();   // p0 ready

    // ---------- iterations: MFMA then fused epilogue+softmax into p[next] ----------
    // 2-deep skew: a wave writing buf[(it+1)&1] can only coexist with a wave
    // still reading buf[it&1] -> disjoint buffers, no WAR hazard. BR region is
    // read-only during iterations.
    f32x4 acc[4];
    for (int it = 0; it < ITER; ++it) {
        unsigned short* pbuf = SH + (it & 1) * RSZ;
#pragma unroll
        for (int nt = 0; nt < 4; ++nt) {
            acc[nt][0] = 0.f; acc[nt][1] = 0.f; acc[nt][2] = 0.f; acc[nt][3] = 0.f;
        }
#pragma unroll
        for (int kk = 0; kk < 2; ++kk) {
            bf16x8 aL = *(const bf16x8*)(pbuf + paL_off + kk * 32);
            bf16x8 aR = *(const bf16x8*)(pbuf + paR_off + kk * 32);
#pragma unroll
            for (int nt = 0; nt < 4; ++nt) {
                // bR fragment from persistent LDS (16-bit imm offsets off bRbase)
                bf16x8 bRf = *(const bf16x8*)(bRbase + nt * 16 * SB + kk * 32);
                acc[nt] = __builtin_amdgcn_mfma_f32_16x16x32_bf16(aL, bL[kk][nt], acc[nt], 0, 0, 0);
                acc[nt] = __builtin_amdgcn_mfma_f32_16x16x32_bf16(aR, bRf, acc[nt], 0, 0, 0);
            }
        }
        if (it < ITER - 1) {
            // fused epilogue+softmax: e = 2^(umm' + mk'*acc), no q[] live set
            unsigned short* nbuf = SH + ((it + 1) & 1) * RSZ;
#pragma unroll
            for (int reg = 0; reg < 4; ++reg) {
                bool valid = (unsigned)(grow0 + reg) < (unsigned)SEQ;
                softmax_row_write(umm[0][reg] + mk[reg] * acc[0][reg],
                                  umm[1][reg] + mk[reg] * acc[1][reg],
                                  umm[2][reg] + mk[reg] * acc[2][reg],
                                  umm[3][reg] + mk[reg] * acc[3][reg],
                                  v3, valid, nbuf + pw_off + reg * SP);
            }
            __syncthreads();   // p[it+1] ready; MFMA(it) reads all done block-wide
        }
    }

    // ---------- staged store: pack [row][50] fp32 in LDS, full-line streaming copy ----------
    __syncthreads();   // all MFMA/LDS reads done; safe to repurpose p0+p1 as stage
    const int gcnt = (SEQ - s0 < CORE) ? (SEQ - s0) : CORE;
#pragma unroll
    for (int reg = 0; reg < 4; ++reg) {
        int g = tile0 + quad * 4 + reg;
        if (g >= s0 && g < s0 + gcnt) {
#pragma unroll
            for (int nt = 0; nt < 4; ++nt) {
                int c = nt * 16 + nloc;
                if (c < L)
                    stage[(g - s0) * L + c] = (umm[nt][reg] + mk[reg] * acc[nt][reg]) * LN2;
            }
        }
    }
    __syncthreads();
    {
        const int ocnt = gcnt * L;                                 // multiple of 4
        f32x4* dst = (f32x4*)(out + ((size_t)nb * SEQ + s0) * L);  // 16B-aligned
        const f32x4* src = (const f32x4*)stage;
        for (int i = tid; i < (ocnt >> 2); i += 256) dst[i] = src[i];
    }
}

extern "C" void kernel_launch(void* const* d_in, const int* in_sizes, int n_in,
                              void* d_out, int out_size, void* d_ws, size_t ws_size,
                              hipStream_t stream) {
    const float* unary  = (const float*)d_in[0];
    const float* mask   = (const float*)d_in[1];
    const float* trans  = (const float*)d_in[2];
    const float* tstart = (const float*)d_in[3];
    const float* tend   = (const float*)d_in[4];
    float* out = (float*)d_out;

    dim3 grid((SEQ + CORE - 1) / CORE, N_BATCH);   // 36 x 256
    mfvi_kernel<<<grid, dim3(256), 0, stream>>>(unary, mask, trans, tstart, tend, out);
}

// Round 6
// 215.917 us; speedup vs baseline: 1.2502x; 1.2502x over previous
//
#include <hip/hip_runtime.h>

#define N_BATCH 256
#define SEQ     2048
#define NTHREADS 512                // 8 waves -> 128-row tile
#define TROWS   128                 // tile rows (8 waves x 16)
#define CORE    122                 // output rows per block (TROWS - 2*HALO)
#define HALO    3                   // iteration dependency radius
#define SP      72                  // p row stride in bf16 (144 B, 16B-aligned)
#define SB      72                  // B row stride in bf16
#define ITER    3
#define RSZ     (TROWS * SP)        // 9216 shorts = 18432 B per p region

#define L       50
#define L2E 1.4426950408889634f
#define LN2 0.6931471805599453f

typedef __attribute__((ext_vector_type(8))) short bf16x8;
typedef __attribute__((ext_vector_type(4))) float f32x4;

__device__ __forceinline__ unsigned short f2b(float f) {
    unsigned int u = __builtin_bit_cast(unsigned int, f);
    u += 0x7FFFu + ((u >> 16) & 1u);            // RTNE
    return (unsigned short)(u >> 16);
}

// gfx950 packed f32->bf16 (RTNE)
__device__ __forceinline__ unsigned int cvt_pk_bf16(float lo, float hi) {
    unsigned int r;
    asm("v_cvt_pk_bf16_f32 %0, %1, %2" : "=v"(r) : "v"(lo), "v"(hi));
    return r;
}

template <int CTRL>
__device__ __forceinline__ float dpp_mov_f32(float x) {
    int xi = __builtin_bit_cast(int, x);
    int r  = __builtin_amdgcn_update_dpp(xi, xi, CTRL, 0xF, 0xF, false);
    return __builtin_bit_cast(float, r);
}

// 16-lane (nloc) sum entirely on the VALU:
// quad_perm xor1 (0xB1), xor2 (0x4E), then row_ror:4 (0x124) + row_ror:8 (0x128)
__device__ __forceinline__ float rowsum16(float s) {
    s += dpp_mov_f32<0xB1>(s);
    s += dpp_mov_f32<0x4E>(s);
    s += dpp_mov_f32<0x124>(s);
    s += dpp_mov_f32<0x128>(s);
    return s;
}

__device__ __forceinline__ float fexp2(float x) {
#if __has_builtin(__builtin_amdgcn_exp2f)
    return __builtin_amdgcn_exp2f(x);
#else
    return __expf(x * LN2);
#endif
}

// softmax of one 50-wide row slice (log2e domain) + normalized bf16 pack +
// single conflict-free ds_write_b64. x0..x3 are this lane's 4 elements
// (cols nloc, 16+nloc, 32+nloc, 48+nloc); v3 masks cols >= 50.
__device__ __forceinline__ void softmax_row_write(
    float x0, float x1, float x2, float x3, bool v3, bool valid,
    unsigned short* dst)
{
    float e0 = fexp2(x0);
    float e1 = fexp2(x1);
    float e2 = fexp2(x2);
    float e3 = v3 ? fexp2(x3) : 0.f;
    float s  = rowsum16(e0 + e1 + e2 + e3);
    float inv = valid ? __builtin_amdgcn_rcpf(s) : 0.f;   // 0 -> OOR rows give p=0
    uint2 pk;
    pk.x = cvt_pk_bf16(e0 * inv, e1 * inv);
    pk.y = cvt_pk_bf16(e2 * inv, e3 * inv);
    *(uint2*)dst = pk;
}

// k-dim permutation: k' = (k&15)*4 + (k>>4). Applied to BOTH p writes and
// BL/BR staging -> contraction unchanged (bijection on k), but each lane's 4
// softmax outputs land contiguously -> one ds_write_b64, conflict-free.
#define KPERM(k) ((((k) & 15) << 2) | ((k) >> 4))

// waves_per_eu PINNED (4,4): 128-reg budget, the allocation PROVEN spill-free
// in round 4 (WRITE_SIZE byte-exact ideal). Occupancy axis is closed:
//  - (4,8) range  -> allocator gambled on 8 waves/EU, massive spill (round 2)
//  - (4,4) + q[] live across barriers -> 1-reg spill (round 3)
//  - (5,5) + bR in LDS -> ~96-reg budget, 5-reg spill, +184 MB writes (round 5)
// Tripwire: WRITE_SIZE > ~110 MB means spill -> revert to round-4 shape.
__global__ __attribute__((amdgpu_waves_per_eu(4, 4))) __launch_bounds__(NTHREADS)
void mfvi_kernel(
    const float* __restrict__ unary,
    const float* __restrict__ mask,
    const float* __restrict__ trans,   // [L][L]
    const float* __restrict__ tstart,  // [L]
    const float* __restrict__ tend,    // [L]
    float* __restrict__ out)
{
    // LDS (shorts): [p0: 0..9216) [p1: 9216..18432)  = 36864 B total
    //  - BL/BR staging (4608 shorts each) transient inside the p0 region
    //  - p double-buffer p0/p1 -> ONE barrier per iteration
    //  - fp32 out-stage (24400 B) reuses p0+p1 at the end
    __shared__ __attribute__((aligned(16))) unsigned short SH[2 * RSZ];
    unsigned short* BLs = SH;               // transient: BL[n][k'] = T[k][n]
    unsigned short* BRs = SH + 64 * SB;     // transient: BR[n][k'] = T[n][k]
    float* stage = (float*)SH;

    const int tid   = threadIdx.x;
    const int lane  = tid & 63;
    const int wave  = tid >> 6;             // 0..7
    const int nloc  = lane & 15;
    const int quad  = lane >> 4;
    const int nb    = blockIdx.y;
    const int s0    = blockIdx.x * CORE;
    const int tile0 = s0 - HALO + wave * 16;   // global seq row of this wave's tile row 0

    // ---------- early global loads (in flight across LDS setup) ----------
    float uraw[4][4], mk[4], tev[4];
#pragma unroll
    for (int nt = 0; nt < 4; ++nt) {
        int c = nt * 16 + nloc;
        tev[nt] = (c < L) ? tend[c] : 0.f;
    }
#pragma unroll
    for (int reg = 0; reg < 4; ++reg) {
        int g = tile0 + quad * 4 + reg;
        bool in = (unsigned)g < (unsigned)SEQ;
        mk[reg] = in ? mask[nb * SEQ + g] : 0.f;
#pragma unroll
        for (int nt = 0; nt < 4; ++nt) {
            int c = nt * 16 + nloc;
            bool cv = in && (c < L);
            uraw[nt][reg] = cv ? unary[((size_t)nb * SEQ + g) * L + c] : 0.f;
        }
    }

    // ---------- zero BL/BR staging area (pad rows/cols must be finite 0) ----------
    {
        uint4 z; z.x = 0u; z.y = 0u; z.z = 0u; z.w = 0u;
        uint4* p = (uint4*)SH;
        for (int i = tid; i < (2 * 64 * SB) / 8; i += NTHREADS) p[i] = z;
    }
    __syncthreads();

    // ---------- stage T: coalesced read, k-permuted LDS scatter ----------
    for (int i = tid; i < L * L; i += NTHREADS) {
        int r = i / L, c = i - r * L;
        unsigned short v = f2b(trans[i]);
        BLs[c * SB + KPERM(r)] = v;
        BRs[r * SB + KPERM(c)] = v;
    }
    __syncthreads();

    // ---------- B fragments -> registers (64 VGPRs, persistent; wave-invariant) ----------
    bf16x8 bL[2][4], bR[2][4];
#pragma unroll
    for (int kk = 0; kk < 2; ++kk)
#pragma unroll
        for (int nt = 0; nt < 4; ++nt) {
            int off = (nt * 16 + nloc) * SB + kk * 32 + quad * 8;
            bL[kk][nt] = *(const bf16x8*)&BLs[off];
            bR[kk][nt] = *(const bf16x8*)&BRs[off];
        }
    __syncthreads();   // staging dead; p buffers live from here

    // ---------- umm (log2e domain) + initial q in-place in uraw ----------
    // q' = q*log2e; softmax(q) == 2^q' normalized; final out = q'_final * ln2.
    float umm[4][4];
#pragma unroll
    for (int reg = 0; reg < 4; ++reg) {
        int g = tile0 + quad * 4 + reg;
#pragma unroll
        for (int nt = 0; nt < 4; ++nt) {
            float bnd = tev[nt];
            if (g == 0) {                      // exactly one row in the whole grid
                int c = nt * 16 + nloc;
                bnd = (c < L) ? tstart[c] : 0.f;
            }
            float qv  = uraw[nt][reg] * mk[reg];
            uraw[nt][reg] = qv * L2E;                    // q'_init
            umm[nt][reg]  = (qv + bnd) * (mk[reg] * L2E);
        }
        mk[reg] *= L2E;   // fused scale: softmax input = umm' + mk'*acc
    }

    const int myrow = wave * 16 + quad * 4;
    int slL = wave * 16 + nloc - 1; if (slL < 0)        slL = 0;          // clamped
    int slR = wave * 16 + nloc + 1; if (slR > TROWS - 1) slR = TROWS - 1; // don't-care rows
    const int pw_off  = myrow * SP + 4 * nloc;   // b64 write base (8B-aligned)
    const int paL_off = slL * SP + quad * 8;
    const int paR_off = slR * SP + quad * 8;
    const int grow0 = tile0 + quad * 4;
    const bool v3 = (nloc < 2);                  // col 48+nloc < 50

    // ---------- prologue: softmax#1 from q'_init, write p0 ----------
#pragma unroll
    for (int reg = 0; reg < 4; ++reg) {
        bool valid = (unsigned)(grow0 + reg) < (unsigned)SEQ;
        softmax_row_write(uraw[0][reg], uraw[1][reg], uraw[2][reg], uraw[3][reg],
                          v3, valid, SH + pw_off + reg * SP);
    }
    __syncthreads();   // p0 ready

    // ---------- iterations: MFMA then fused epilogue+softmax into p[next] ----------
    // 2-deep skew: a wave writing buf[(it+1)&1] can only coexist with a wave
    // still reading buf[it&1] -> disjoint buffers, no WAR hazard.
    f32x4 acc[4];
    for (int it = 0; it < ITER; ++it) {
        unsigned short* pbuf = SH + (it & 1) * RSZ;
#pragma unroll
        for (int nt = 0; nt < 4; ++nt) {
            acc[nt][0] = 0.f; acc[nt][1] = 0.f; acc[nt][2] = 0.f; acc[nt][3] = 0.f;
        }
#pragma unroll
        for (int kk = 0; kk < 2; ++kk) {
            bf16x8 aL = *(const bf16x8*)(pbuf + paL_off + kk * 32);
            bf16x8 aR = *(const bf16x8*)(pbuf + paR_off + kk * 32);
#pragma unroll
            for (int nt = 0; nt < 4; ++nt) {
                acc[nt] = __builtin_amdgcn_mfma_f32_16x16x32_bf16(aL, bL[kk][nt], acc[nt], 0, 0, 0);
                acc[nt] = __builtin_amdgcn_mfma_f32_16x16x32_bf16(aR, bR[kk][nt], acc[nt], 0, 0, 0);
            }
        }
        if (it < ITER - 1) {
            // fused epilogue+softmax: e = 2^(umm' + mk'*acc), no q[] live set
            unsigned short* nbuf = SH + ((it + 1) & 1) * RSZ;
#pragma unroll
            for (int reg = 0; reg < 4; ++reg) {
                bool valid = (unsigned)(grow0 + reg) < (unsigned)SEQ;
                softmax_row_write(umm[0][reg] + mk[reg] * acc[0][reg],
                                  umm[1][reg] + mk[reg] * acc[1][reg],
                                  umm[2][reg] + mk[reg] * acc[2][reg],
                                  umm[3][reg] + mk[reg] * acc[3][reg],
                                  v3, valid, nbuf + pw_off + reg * SP);
            }
            __syncthreads();   // p[it+1] ready; MFMA(it) reads all done block-wide
        }
    }

    // ---------- staged store: pack [row][50] fp32 in LDS, full-line streaming copy ----------
    __syncthreads();   // all MFMA reads of SH done; safe to repurpose as stage
    const int gcnt = (SEQ - s0 < CORE) ? (SEQ - s0) : CORE;
#pragma unroll
    for (int reg = 0; reg < 4; ++reg) {
        int g = tile0 + quad * 4 + reg;
        if (g >= s0 && g < s0 + gcnt) {
#pragma unroll
            for (int nt = 0; nt < 4; ++nt) {
                int c = nt * 16 + nloc;
                if (c < L)
                    stage[(g - s0) * L + c] = (umm[nt][reg] + mk[reg] * acc[nt][reg]) * LN2;
            }
        }
    }
    __syncthreads();
    {
        const int ocnt = gcnt * L;                                 // multiple of 2; 122*50/4, 96*50/4 exact
        f32x4* dst = (f32x4*)(out + ((size_t)nb * SEQ + s0) * L);  // 16B-aligned
        const f32x4* src = (const f32x4*)stage;
        for (int i = tid; i < (ocnt >> 2); i += NTHREADS) dst[i] = src[i];
    }
}

extern "C" void kernel_launch(void* const* d_in, const int* in_sizes, int n_in,
                              void* d_out, int out_size, void* d_ws, size_t ws_size,
                              hipStream_t stream) {
    const float* unary  = (const float*)d_in[0];
    const float* mask   = (const float*)d_in[1];
    const float* trans  = (const float*)d_in[2];
    const float* tstart = (const float*)d_in[3];
    const float* tend   = (const float*)d_in[4];
    float* out = (float*)d_out;

    dim3 grid((SEQ + CORE - 1) / CORE, N_BATCH);   // 17 x 256
    mfvi_kernel<<<grid, dim3(NTHREADS), 0, stream>>>(unary, mask, trans, tstart, tend, out);
}